// Round 8
// baseline (320.369 us; speedup 1.0000x reference)
//
#include <hip/hip_runtime.h>
#include <hip/hip_cooperative_groups.h>
#include <math.h>

// WaveLM: logits[b,t,v] = sum_{t'<t} g(id[b,t'], v)
// g(u,v) = 2 * sum_{i,j in 1..H} (A_u/i^dec)(A_v/j^dec) * sinc(2*(f_u*i - f_v*j))
// sinc(2d) = sin(2*pi*d)/(2*pi*d), sinc(0)=1
//
// R13: - COOPERATIVE FUSION: wavelm_g + wavelm_addbase merged into one
//        persistent-block kernel (phase1 compute tiles -> grid.sync() ->
//        phase2 base-sum + RMW). Saves one launch (~25us fixed overhead)
//        and makes the 127MB out-RMW L2-local (phase2 tile == phase1 tile
//        of the SAME block -> same CU -> same XCD L2). segsum crosses XCDs
//        via grid.sync's device fence (L3-coherent).
//      - Grid sized via hipOccupancyMaxActiveBlocksPerMultiprocessor and
//        balanced (k tiles/block, nblk = ceil(NTILE/k)); runtime validates
//        cooperative capacity; non-coop fallback = R12's two-kernel path.
//        NO early returns before grid.sync (wave-uniform skips instead).
//      - Tile compute body IDENTICAL to R12 (packed 2-v/lane, in-register
//        table math, 2 uniform s_loads/token, finite-check guard, GT=16
//        fused segment scan, id-only prefetch).

namespace cg = cooperative_groups;

typedef float v2f __attribute__((ext_vector_type(2)));

constexpr int cB = 4, cT = 512, cV = 8000, cH = 7;
constexpr int GT = 16;                  // tokens per tile == seglen
constexpr int NSEG = cT / GT;           // 32 segments
constexpr int NXB = (cV / 2 + 255) / 256;      // 16 x-tiles
constexpr int NTILE = cB * NSEG * NXB;  // 2048 tiles

__device__ __forceinline__ v2f pk_add(v2f a, v2f b) {
    v2f d; asm("v_pk_add_f32 %0, %1, %2" : "=v"(d) : "v"(a), "v"(b)); return d;
}
__device__ __forceinline__ v2f pk_mul(v2f a, v2f b) {
    v2f d; asm("v_pk_mul_f32 %0, %1, %2" : "=v"(d) : "v"(a), "v"(b)); return d;
}
__device__ __forceinline__ v2f pk_fma(v2f a, v2f b, v2f c) {
    v2f d; asm("v_pk_fma_f32 %0, %1, %2, %3" : "=v"(d) : "v"(a), "v"(b), "v"(c));
    return d;
}
__device__ __forceinline__ float rfl(float x) {
    return __builtin_bit_cast(float,
        __builtin_amdgcn_readfirstlane(__builtin_bit_cast(int, x)));
}

// ---- shared tile bodies -------------------------------------------------

__device__ __forceinline__ void tile_compute(
    const int bs, const int xb, const int* __restrict__ ids,
    const float* __restrict__ freq, const float* __restrict__ amp,
    const float* __restrict__ rp,
    float* __restrict__ out, float* __restrict__ segsum, const int segmode)
{
    const int bt0 = bs * GT;
    const int vh  = xb * 256 + (int)threadIdx.x;    // v-pair index
    const bool valid = (vh * 2 < cV);
    const int vc = valid ? vh : 0;

    // ---- v-side setup once (tab's math, in-register), amortized over GT ----
    const v2f fv = *(const v2f*)(freq + (size_t)vc * 2);
    const v2f Av = *(const v2f*)(amp  + (size_t)vc * 2);
    v2f nb[cH], sBw[cH], cBw[cH];
    {
        const float xrx = fv.x - rintf(fv.x);
        const float xry = fv.y - rintf(fv.y);
        const float s1x = __builtin_amdgcn_sinf(xrx);
        const float c1x = __builtin_amdgcn_cosf(xrx);
        const float s1y = __builtin_amdgcn_sinf(xry);
        const float c1y = __builtin_amdgcn_cosf(xry);
        float sx = s1x, cx = c1x, sy = s1y, cy = c1y;
#pragma unroll
        for (int k = 0; k < cH; ++k) {
            if (k) {
                const float spx = sx, cpx = cx, spy = sy, cpy = cy;
                sx = fmaf(spx, c1x,  cpx * s1x);
                cx = fmaf(cpx, c1x, -(spx * s1x));
                sy = fmaf(spy, c1y,  cpy * s1y);
                cy = fmaf(cpy, c1y, -(spy * s1y));
            }
            const float wx = Av.x * rp[k];          // tab plane 14+k
            const float wy = Av.y * rp[k];
            const float wsx = wx * 0.15915494309189535f;  // w/(2pi)
            const float wsy = wy * 0.15915494309189535f;
            sBw[k].x = sx * wsx;  sBw[k].y = sy * wsy;
            cBw[k].x = cx * wsx;  cBw[k].y = cy * wsy;
            nb[k].x = -(fv.x * (float)(k + 1));     // tab plane 21+k, negated
            nb[k].y = -(fv.y * (float)(k + 1));
        }
    }

    v2f acc;  acc.x = 0.f;  acc.y = 0.f;            // running segment prefix

    int idc = ids[bt0];                             // current token id (SGPR)
    for (int g = 0; g < GT; ++g) {
        // prefetch only the NEXT id (1 SGPR); breaks the id->load serial chain
        const int idn = (g + 1 < GT) ? ids[bt0 + g + 1] : idc;

        // u-side: 2 wave-uniform scalar loads; sin/cos computed (tab's ops)
        const float fu = freq[idc];
        const float Au = amp[idc];
        const float xru = fu - rintf(fu);
        const float s1u = rfl(__builtin_amdgcn_sinf(xru));
        const float c1u = rfl(__builtin_amdgcn_cosf(xru));

        float accx = 0.f, accy = 0.f;
        float su = s1u, cu = c1u;                   // sin/cos(2pi f (i+1))
#pragma unroll
        for (int i = 0; i < cH; ++i) {
            if (i) { const float sp = su, cp = cu;
                     su = fmaf(sp, c1u,  cp * s1u);
                     cu = fmaf(cp, c1u, -(sp * s1u)); }
            const float au = fu * (float)(i + 1);   // same op as tab plane 21
            v2f ai;  ai.x = au;  ai.y = au;
            v2f d[cH], p[cH];
#pragma unroll
            for (int j = 0; j < cH; ++j) d[j] = pk_add(ai, nb[j]);
            p[0] = d[0];
#pragma unroll
            for (int j = 1; j < cH; ++j) p[j] = pk_mul(p[j-1], d[j]);
            const float ptot = p[6].x * p[6].y;
            const float rt = __builtin_amdgcn_rcpf(ptot);
            v2f r;  r.x = rt * p[6].y;  r.y = rt * p[6].x;   // 1/p6 per comp
            v2f accS = (v2f)0.f, accC = (v2f)0.f;
#pragma unroll
            for (int j = cH - 1; j >= 1; --j) {
                const v2f inv = pk_mul(r, p[j-1]);
                accS = pk_fma(cBw[j], inv, accS);
                accC = pk_fma(sBw[j], inv, accC);
                r = pk_mul(r, d[j]);
            }
            accS = pk_fma(cBw[0], r, accS);
            accC = pk_fma(sBw[0], r, accC);
            // sum_j sn_j*inv_j = su*accS - cu*accC  (per component)
            const float tx = fmaf(su, accS.x, -(cu * accC.x));
            const float ty = fmaf(su, accS.y, -(cu * accC.y));
            accx = fmaf(rp[i], tx, accx);
            accy = fmaf(rp[i], ty, accy);
        }

        // rare guarded path. Any d==0 / underflow-to-0 / overflow produces
        // inf or NaN in accx/accy (rcp(0)=inf; inf*0=NaN; finite overflow of
        // intermediates impossible: |p6| <= ~1e16). NaN fails |x|<1e30 too.
        if (!(fabsf(accx) < 1e30f) || !(fabsf(accy) < 1e30f)) {
            accx = 0.f;  accy = 0.f;
            float s2 = s1u, c2 = c1u;
#pragma unroll
            for (int i = 0; i < cH; ++i) {
                if (i) { const float sp = s2, cp = c2;
                         s2 = fmaf(sp, c1u,  cp * s1u);
                         c2 = fmaf(cp, c1u, -(sp * s1u)); }
                const float au = fu * (float)(i + 1);
                float ax = 0.f, ay = 0.f;
#pragma unroll
                for (int j = 0; j < cH; ++j) {
                    const float wxx = Av.x * rp[j];     // tab plane 14+j
                    const float wyy = Av.y * rp[j];
                    const float dx = au + nb[j].x;
                    const float dy = au + nb[j].y;
                    const float snx = fmaf(s2, cBw[j].x, -(c2 * sBw[j].x));
                    const float sny = fmaf(s2, cBw[j].y, -(c2 * sBw[j].y));
                    float qx = snx * __builtin_amdgcn_rcpf(dx);
                    float qy = sny * __builtin_amdgcn_rcpf(dy);
                    qx = (dx == 0.f) ? wxx : qx;
                    qy = (dy == 0.f) ? wyy : qy;
                    ax += qx;  ay += qy;
                }
                accx = fmaf(rp[i], ax, accx);
                accy = fmaf(rp[i], ay, accy);
            }
        }

        if (valid) {
            const float A2 = 2.f * Au;
            v2f res;  res.x = A2 * accx;  res.y = A2 * accy;
            const size_t o = (size_t)(bt0 + g) * cV + (size_t)vh * 2;
            // segmode: write shifted local prefix; else raw value
            v2f wv;  wv.x = segmode ? acc.x : res.x;
                     wv.y = segmode ? acc.y : res.y;
            *(v2f*)(out + o) = wv;
            acc = pk_add(acc, res);
        }

        idc = idn;
    }

    if (valid && segmode)
        *(v2f*)(segsum + (size_t)bs * cV + (size_t)vh * 2) = acc;
}

__device__ __forceinline__ void tile_addbase(
    const int bs, const int xb,
    float* __restrict__ out, const float* __restrict__ segsum)
{
    const int b   = bs >> 5;             // NSEG = 32
    const int seg = bs & (NSEG - 1);
    const int vh  = xb * 256 + (int)threadIdx.x;
    const bool valid = (vh * 2 < cV);
    const int vc = valid ? vh : 0;

    const v2f* ss = (const v2f*)segsum;
    v2f base;  base.x = 0.f;  base.y = 0.f;
    for (int s = 0; s < seg; ++s)
        base = pk_add(base, ss[(size_t)(b * NSEG + s) * (cV / 2) + vc]);

    if (valid) {
        v2f* op = (v2f*)out;
        const size_t o0 = (size_t)(b * cT + seg * GT) * (cV / 2) + (size_t)vh;
#pragma unroll
        for (int k = 0; k < GT; ++k) {
            v2f x = op[o0 + (size_t)k * (cV / 2)];
            op[o0 + (size_t)k * (cV / 2)] = pk_add(x, base);
        }
    }
}

__device__ __forceinline__ void build_rp(const float* decay_p, float* rp)
{
    const float decay = decay_p[0];
    const float q2 = __builtin_amdgcn_exp2f(-decay);
    const float q3 = __builtin_amdgcn_exp2f(-decay * 1.5849625007f);
    const float q5 = __builtin_amdgcn_exp2f(-decay * 2.3219280949f);
    const float q7 = __builtin_amdgcn_exp2f(-decay * 2.8073549221f);
    rp[0] = 1.f;  rp[1] = q2;     rp[2] = q3;  rp[3] = q2 * q2;
    rp[4] = q5;   rp[5] = q2 * q3; rp[6] = q7;
}

// ---- cooperative fused kernel ------------------------------------------

__global__ __launch_bounds__(256) void wavelm_fused(
    const int* __restrict__ ids, const float* __restrict__ freq,
    const float* __restrict__ amp, const float* __restrict__ decay_p,
    float* __restrict__ out, float* __restrict__ segsum)
{
    float rp[cH];
    build_rp(decay_p, rp);
    const int nblk = gridDim.x;

    // phase 1: compute tiles (local prefix + segsum). No returns anywhere.
    for (int t = blockIdx.x; t < NTILE; t += nblk) {
        const int bs = t >> 4;               // NXB = 16
        const int xb = t & (NXB - 1);
        // wave-uniform skip of fully-invalid waves (no return: must reach sync)
        if ((xb * 256 + (int)(threadIdx.x & 192u)) * 2 < cV)
            tile_compute(bs, xb, ids, freq, amp, rp, out, segsum, 1);
    }

    __threadfence();                          // writes -> device scope (L3)
    cg::this_grid().sync();

    // phase 2: add segment bases. Same t->block mapping as phase 1, so the
    // RMW rows were written by THIS block -> same CU -> own-XCD L2 hits.
    for (int t = blockIdx.x; t < NTILE; t += nblk) {
        const int bs = t >> 4;
        const int xb = t & (NXB - 1);
        if ((bs & (NSEG - 1)) == 0) continue; // seg 0: base is zero, done
        if ((xb * 256 + (int)(threadIdx.x & 192u)) * 2 < cV)
            tile_addbase(bs, xb, out, segsum);
    }
}

// ---- non-cooperative fallback (R12 path) --------------------------------

__global__ __launch_bounds__(256) void wavelm_g(
    const int* __restrict__ ids, const float* __restrict__ freq,
    const float* __restrict__ amp, const float* __restrict__ decay_p,
    float* __restrict__ out, float* __restrict__ segsum, const int segmode)
{
    const int bs = blockIdx.y, xb = blockIdx.x;
    if ((xb * 256 + (int)(threadIdx.x & 192u)) * 2 >= cV) return;
    float rp[cH];
    build_rp(decay_p, rp);
    tile_compute(bs, xb, ids, freq, amp, rp, out, segsum, segmode);
}

__global__ __launch_bounds__(256) void wavelm_addbase(
    float* __restrict__ out, const float* __restrict__ segsum)
{
    const int bs = blockIdx.y, xb = blockIdx.x;
    if ((bs & (NSEG - 1)) == 0) return;
    if ((xb * 256 + (int)(threadIdx.x & 192u)) * 2 >= cV) return;
    tile_addbase(bs, xb, out, segsum);
}

// fallback full-chain scan (ws too small for segsum)
__global__ __launch_bounds__(256) void wavelm_scan(float* __restrict__ out)
{
    const int g = blockIdx.x * blockDim.x + threadIdx.x;
    if (g >= cB * cV) return;
    const int b = g / cV;
    const int v = g - b * cV;
    float* p = out + (size_t)b * cT * cV + v;
    float acc = 0.f;
#pragma unroll 8
    for (int t = 0; t < cT; ++t) {
        const float c = p[(size_t)t * cV];
        p[(size_t)t * cV] = acc;
        acc += c;
    }
}

extern "C" void kernel_launch(void* const* d_in, const int* in_sizes, int n_in,
                              void* d_out, int out_size, void* d_ws, size_t ws_size,
                              hipStream_t stream)
{
    const int*   ids  = (const int*)d_in[0];
    const float* freq = (const float*)d_in[1];
    const float* amp  = (const float*)d_in[2];
    const float* dec  = (const float*)d_in[3];
    float* out = (float*)d_out;
    float* segsum = (float*)d_ws;                        // 4*32*8000*4 = 4 MB

    const size_t seg_b = (size_t)cB * NSEG * cV * sizeof(float);
    const int segmode = (seg_b <= ws_size) ? 1 : 0;

    if (segmode) {
        int dev = 0;
        (void)hipGetDevice(&dev);
        int coop = 0, nbcu = 0, ncu = 0;
        (void)hipDeviceGetAttribute(&coop, hipDeviceAttributeCooperativeLaunch, dev);
        (void)hipOccupancyMaxActiveBlocksPerMultiprocessor(&nbcu, wavelm_fused, 256, 0);
        (void)hipDeviceGetAttribute(&ncu, hipDeviceAttributeMultiprocessorCount, dev);

        bool done = false;
        if (coop && nbcu > 0 && ncu > 0) {
            const int cap = nbcu * ncu;
            const int k = (NTILE + cap - 1) / cap;       // tiles per block
            const int nblk = (NTILE + k - 1) / k;        // balanced grid
            const int* a0 = ids;  const float* a1 = freq;
            const float* a2 = amp;  const float* a3 = dec;
            float* a4 = out;  float* a5 = segsum;
            void* args[6] = {&a0, &a1, &a2, &a3, &a4, &a5};
            hipError_t e = hipLaunchCooperativeKernel(
                wavelm_fused, dim3(nblk), dim3(256), args, 0, stream);
            done = (e == hipSuccess);
        }
        if (!done) {
            dim3 grid(NXB, cB * NSEG);                   // 16 x 128
            wavelm_g<<<grid, dim3(256), 0, stream>>>(ids, freq, amp, dec,
                                                     out, segsum, 1);
            wavelm_addbase<<<grid, dim3(256), 0, stream>>>(out, segsum);
        }
    } else {
        dim3 grid(NXB, cB * NSEG);
        wavelm_g<<<grid, dim3(256), 0, stream>>>(ids, freq, amp, dec,
                                                 out, (float*)d_ws, 0);
        const int nchains = cB * cV;
        wavelm_scan<<<(nchains + 255) / 256, dim3(256), 0, stream>>>(out);
    }
}